// Round 7
// baseline (91.206 us; speedup 1.0000x reference)
//
#include <hip/hip_runtime.h>
#include <stdint.h>

#define HASH_T 524288u
#define HASH_MASK (HASH_T - 1u)
#define PRIME1 2654435761u
#define PRIME2 805459861u

typedef float f32x2 __attribute__((ext_vector_type(2)));

// Output: [B][32][256][256] f32, channel c = 2*l + f.
// Thread = 2 consecutive pixels (b, i, j0, j0+1) for HALF the levels.
//   half0 (blockIdx even): levels 0..10  -- s <= 0.9014, so the 2 pixels'
//          x-corners span at most 3 columns -> 6 fetches per level per 2px.
//   half1 (blockIdx odd):  levels 11..15 -- random, 4 fetches per pixel.
// Grid: 8192 waves (fills the chip; R5 showed 4096 is latency-starved).
// Lane-addresses/px: 53 gathers + 8 stores = 61 (vs 96 in the R2 kernel).
__global__ __launch_bounds__(256) void lia_hashgrid_kernel(
    const float* __restrict__ x0,        // [B]
    const float* __restrict__ y0,        // [B]
    const float* __restrict__ tables,    // [T][2]
    const uint32_t* __restrict__ seeds,  // [16]
    const float* __restrict__ level_N,   // [16]
    const int* __restrict__ tile_p,      // scalar
    float* __restrict__ out)             // [B][32][65536]
{
    const int bid  = blockIdx.x;
    const int half = bid & 1;            // block-uniform
    const int rest = bid >> 1;           // 0..1023
    const int b    = rest >> 7;          // 0..7
    const int tid  = threadIdx.x;
    const int i    = (((rest & 127) << 1) | (tid >> 7));  // 0..255
    const int j0   = (tid & 127) << 1;                    // 0,2,..,254

    const float inv_tile = 1.0f / (float)(*tile_p);   // 1/1024, exact
    const float xb = x0[b];
    const float py = (float)i + y0[b];

    const float2* __restrict__ tab2 = (const float2*)tables;
    float* outp = out + (size_t)b * 32u * 65536u + (size_t)(i * 256 + j0);

    if (half == 0) {
        // ---- levels 0..10: 3 x-columns shared by both pixels ----
        #pragma unroll
        for (int l = 0; l < 11; ++l) {
            const float s = level_N[l] * inv_tile;
            const uint32_t seed = seeds[l];

            const float yn = py * s;
            const float fy = yn - floorf(yn);
            const uint32_t iy0 = (uint32_t)(int)floorf(yn);
            const uint32_t hy0 = iy0 * PRIME2;
            const uint32_t hy1 = hy0 + PRIME2;
            const float gy = 1.0f - fy;

            const float xnA = ((float)j0 + xb) * s;
            const float xnB = ((float)(j0 + 1) + xb) * s;
            const float flxA = floorf(xnA);
            const float flxB = floorf(xnB);
            const float fxA = xnA - flxA;
            const float fxB = xnB - flxB;
            const uint32_t X = (uint32_t)(int)flxA;
            const bool dB = ((int)flxB - (int)flxA) != 0;   // 0 or 1

            const uint32_t hx0 = X * PRIME1;
            const uint32_t hx1 = hx0 + PRIME1;
            const uint32_t hx2 = hx1 + PRIME1;

            const float2 t0a = tab2[(hx0 ^ hy0 ^ seed) & HASH_MASK];
            const float2 t1a = tab2[(hx1 ^ hy0 ^ seed) & HASH_MASK];
            const float2 t2a = tab2[(hx2 ^ hy0 ^ seed) & HASH_MASK];
            const float2 t0b = tab2[(hx0 ^ hy1 ^ seed) & HASH_MASK];
            const float2 t1b = tab2[(hx1 ^ hy1 ^ seed) & HASH_MASK];
            const float2 t2b = tab2[(hx2 ^ hy1 ^ seed) & HASH_MASK];

            // pixel A (d=0)
            const float gxA = 1.0f - fxA;
            const float w00A = gxA * gy, w10A = fxA * gy;
            const float w01A = gxA * fy, w11A = fxA * fy;
            const float e0A = w00A * t0a.x + w10A * t1a.x + w01A * t0b.x + w11A * t1b.x;
            const float e1A = w00A * t0a.y + w10A * t1a.y + w01A * t0b.y + w11A * t1b.y;

            // pixel B (d = dB)
            const float2 f00 = dB ? t1a : t0a;
            const float2 f10 = dB ? t2a : t1a;
            const float2 f01 = dB ? t1b : t0b;
            const float2 f11 = dB ? t2b : t1b;
            const float gxB = 1.0f - fxB;
            const float w00B = gxB * gy, w10B = fxB * gy;
            const float w01B = gxB * fy, w11B = fxB * fy;
            const float e0B = w00B * f00.x + w10B * f10.x + w01B * f01.x + w11B * f11.x;
            const float e1B = w00B * f00.y + w10B * f10.y + w01B * f01.y + w11B * f11.y;

            f32x2 v0 = {e0A, e0B};
            f32x2 v1 = {e1A, e1B};
            __builtin_nontemporal_store(v0, (f32x2*)(outp + (size_t)(2 * l) * 65536u));
            __builtin_nontemporal_store(v1, (f32x2*)(outp + (size_t)(2 * l + 1) * 65536u));
        }
    } else {
        // ---- levels 11..15: random, per-pixel fetches ----
        #pragma unroll
        for (int l = 11; l < 16; ++l) {
            const float s = level_N[l] * inv_tile;
            const uint32_t seed = seeds[l];

            const float yn = py * s;
            const float fy = yn - floorf(yn);
            const uint32_t iy0 = (uint32_t)(int)floorf(yn);
            const uint32_t hy0 = iy0 * PRIME2;
            const uint32_t hy1 = hy0 + PRIME2;
            const float gy = 1.0f - fy;

            float e0s[2], e1s[2];
            #pragma unroll
            for (int p = 0; p < 2; ++p) {
                const float xn = ((float)(j0 + p) + xb) * s;
                const float flx = floorf(xn);
                const float fx = xn - flx;
                const uint32_t ix0 = (uint32_t)(int)flx;
                const uint32_t hx0 = ix0 * PRIME1;
                const uint32_t hx1 = hx0 + PRIME1;

                const float2 f00 = tab2[(hx0 ^ hy0 ^ seed) & HASH_MASK];
                const float2 f10 = tab2[(hx1 ^ hy0 ^ seed) & HASH_MASK];
                const float2 f01 = tab2[(hx0 ^ hy1 ^ seed) & HASH_MASK];
                const float2 f11 = tab2[(hx1 ^ hy1 ^ seed) & HASH_MASK];

                const float gx = 1.0f - fx;
                const float w00 = gx * gy, w10 = fx * gy;
                const float w01 = gx * fy, w11 = fx * fy;
                e0s[p] = w00 * f00.x + w10 * f10.x + w01 * f01.x + w11 * f11.x;
                e1s[p] = w00 * f00.y + w10 * f10.y + w01 * f01.y + w11 * f11.y;
            }
            f32x2 v0 = {e0s[0], e0s[1]};
            f32x2 v1 = {e1s[0], e1s[1]};
            __builtin_nontemporal_store(v0, (f32x2*)(outp + (size_t)(2 * l) * 65536u));
            __builtin_nontemporal_store(v1, (f32x2*)(outp + (size_t)(2 * l + 1) * 65536u));
        }
    }
}

extern "C" void kernel_launch(void* const* d_in, const int* in_sizes, int n_in,
                              void* d_out, int out_size, void* d_ws, size_t ws_size,
                              hipStream_t stream) {
    const float*    x0      = (const float*)d_in[0];
    const float*    y0      = (const float*)d_in[1];
    const float*    tables  = (const float*)d_in[2];
    const uint32_t* seeds   = (const uint32_t*)d_in[3];
    const float*    level_N = (const float*)d_in[4];
    const int*      tile_p  = (const int*)d_in[6];   // complete_tile_size
    float*          out     = (float*)d_out;

    const int B = in_sizes[0];                       // 8
    // blocks: B * 128 row-pairs * 2 halves; 256 thr = 2 rows x 128 2px-quads
    const int n_blocks = B * 128 * 2;                // 2048 blocks = 8192 waves

    lia_hashgrid_kernel<<<n_blocks, 256, 0, stream>>>(
        x0, y0, tables, seeds, level_N, tile_p, out);
}

// Round 8
// 69.604 us; speedup vs baseline: 1.3104x; 1.3104x over previous
//
#include <hip/hip_runtime.h>
#include <stdint.h>

#define HASH_T 524288u
#define HASH_MASK (HASH_T - 1u)
#define PRIME1 2654435761u
#define PRIME2 805459861u

// Output: [B][32][256][256] f32, channel c = 2*l + f.
// Thread = one (b, i, j) pixel for a THIRD of the levels, interleaved mod 3
// so wave types have balanced unique-line work:
//   third0: levels 0,3,6,9,12,15   third1: 1,4,7,10,13   third2: 2,5,8,11,14
// 24576 waves total (R2's 16384 was the best so far; wave count is the only
// knob that has moved perf). Levels processed in PAIRS with all 8 gathers
// issued before any consumption (8-load cluster = 16 VGPR, small enough that
// the scheduler accepts it).

#define HASHES(l, h00, h10, h01, h11, FX, FY)                          \
    float FX, FY; uint32_t h00, h10, h01, h11;                         \
    {                                                                  \
        const float s_ = level_N[l] * inv_tile;                        \
        const float xn_ = px * s_, yn_ = py * s_;                      \
        const int ix_ = (int)xn_, iy_ = (int)yn_;   /* coords >= 0 */  \
        FX = xn_ - (float)ix_; FY = yn_ - (float)iy_;                  \
        const uint32_t hx0_ = (uint32_t)ix_ * PRIME1, hx1_ = hx0_ + PRIME1; \
        const uint32_t hy0_ = (uint32_t)iy_ * PRIME2, hy1_ = hy0_ + PRIME2; \
        const uint32_t sd_ = seeds[l];                                 \
        h00 = (hx0_ ^ hy0_ ^ sd_) & HASH_MASK;                         \
        h10 = (hx1_ ^ hy0_ ^ sd_) & HASH_MASK;                         \
        h01 = (hx0_ ^ hy1_ ^ sd_) & HASH_MASK;                         \
        h11 = (hx1_ ^ hy1_ ^ sd_) & HASH_MASK;                         \
    }

#define LOADS(h00, h10, h01, h11, f00, f10, f01, f11)                  \
    const float2 f00 = tab2[h00], f10 = tab2[h10],                     \
                 f01 = tab2[h01], f11 = tab2[h11];

#define STOREL(l, FX, FY, f00, f10, f01, f11)                          \
    {                                                                  \
        const float gx_ = 1.0f - FX, gy_ = 1.0f - FY;                  \
        const float w00_ = gx_ * gy_, w10_ = FX * gy_;                 \
        const float w01_ = gx_ * FY,  w11_ = FX * FY;                  \
        const float e0_ = w00_ * f00.x + w10_ * f10.x + w01_ * f01.x + w11_ * f11.x; \
        const float e1_ = w00_ * f00.y + w10_ * f10.y + w01_ * f01.y + w11_ * f11.y; \
        __builtin_nontemporal_store(e0_, outp + (size_t)(2 * (l)) * 65536u);     \
        __builtin_nontemporal_store(e1_, outp + (size_t)(2 * (l) + 1) * 65536u); \
    }

#define PAIR(la, lb)                                                   \
    {                                                                  \
        HASHES(la, a00, a10, a01, a11, fxa, fya)                       \
        HASHES(lb, b00, b10, b01, b11, fxb, fyb)                       \
        LOADS(a00, a10, a01, a11, fa00, fa10, fa01, fa11)              \
        LOADS(b00, b10, b01, b11, fb00, fb10, fb01, fb11)              \
        STOREL(la, fxa, fya, fa00, fa10, fa01, fa11)                   \
        STOREL(lb, fxb, fyb, fb00, fb10, fb01, fb11)                   \
    }

#define SINGLE(l)                                                      \
    {                                                                  \
        HASHES(l, c00, c10, c01, c11, fxc, fyc)                        \
        LOADS(c00, c10, c01, c11, fc00, fc10, fc01, fc11)              \
        STOREL(l, fxc, fyc, fc00, fc10, fc01, fc11)                    \
    }

__global__ __launch_bounds__(256) void lia_hashgrid_kernel(
    const float* __restrict__ x0,        // [B]
    const float* __restrict__ y0,        // [B]
    const float* __restrict__ tables,    // [T][2]
    const uint32_t* __restrict__ seeds,  // [16]
    const float* __restrict__ level_N,   // [16]
    const int* __restrict__ tile_p,      // scalar
    float* __restrict__ out)             // [B][32][65536]
{
    const int gid = blockIdx.x * 256 + threadIdx.x;
    const int j = gid & 255;
    const int i = (gid >> 8) & 255;
    const int bt = gid >> 16;            // 0..23, block-uniform
    const int b = bt / 3;                // 0..7
    const int third = bt - 3 * b;        // 0..2

    const float inv_tile = 1.0f / (float)(*tile_p);   // 1/1024, exact
    const float px = (float)j + x0[b];
    const float py = (float)i + y0[b];

    const float2* __restrict__ tab2 = (const float2*)tables;
    float* outp = out + (size_t)b * 32u * 65536u + (size_t)(i * 256 + j);

    if (third == 0) {
        PAIR(0, 3)
        PAIR(6, 9)
        PAIR(12, 15)
    } else if (third == 1) {
        PAIR(1, 4)
        PAIR(7, 10)
        SINGLE(13)
    } else {
        PAIR(2, 5)
        PAIR(8, 11)
        SINGLE(14)
    }
}

extern "C" void kernel_launch(void* const* d_in, const int* in_sizes, int n_in,
                              void* d_out, int out_size, void* d_ws, size_t ws_size,
                              hipStream_t stream) {
    const float*    x0      = (const float*)d_in[0];
    const float*    y0      = (const float*)d_in[1];
    const float*    tables  = (const float*)d_in[2];
    const uint32_t* seeds   = (const uint32_t*)d_in[3];
    const float*    level_N = (const float*)d_in[4];
    const int*      tile_p  = (const int*)d_in[6];   // complete_tile_size
    float*          out     = (float*)d_out;

    const int B = in_sizes[0];                 // 8
    const int n_blocks = B * 3 * 256;          // 6144 blocks = 24576 waves

    lia_hashgrid_kernel<<<n_blocks, 256, 0, stream>>>(
        x0, y0, tables, seeds, level_N, tile_p, out);
}

// Round 9
// 65.411 us; speedup vs baseline: 1.3943x; 1.0641x over previous
//
#include <hip/hip_runtime.h>
#include <stdint.h>

#define HASH_MASK 524287u
#define PRIME1 2654435761u
#define PRIME2 805459861u

// Output: [B][32][256][256] f32, channel c = 2*l + f.
// Block = 256 threads = one image row (i) x one level-third.
//   thirds: {0,3,6,9,12,15} / {1,4,7,10,13} / {2,5,8,11,14}
// Coarse 4 levels of each third are staged in LDS (strip = 2 y-rows x <=348
// x-cells <= 992 float2 = 8KB), interpolation reads LDS (ds pipe) instead of
// issuing TA gather lanes. Fine levels (12,15 / 13 / 14) gather directly.
// Rationale: TA saturates at ~1.2 lane-addresses/cyc/CU (R1/R2/R8); LDS
// offload cuts TA lanes/px from 96 to ~56 while keeping 24576 waves.

#define HASHES(l, h00, h10, h01, h11, FX, FY)                          \
    float FX, FY; uint32_t h00, h10, h01, h11;                         \
    {                                                                  \
        const float s_ = level_N[l] * inv_tile;                        \
        const float xn_ = px * s_, yn_ = py * s_;                      \
        const int ix_ = (int)xn_, iy_ = (int)yn_;   /* coords >= 0 */  \
        FX = xn_ - (float)ix_; FY = yn_ - (float)iy_;                  \
        const uint32_t hx0_ = (uint32_t)ix_ * PRIME1, hx1_ = hx0_ + PRIME1; \
        const uint32_t hy0_ = (uint32_t)iy_ * PRIME2, hy1_ = hy0_ + PRIME2; \
        const uint32_t sd_ = seeds[l];                                 \
        h00 = (hx0_ ^ hy0_ ^ sd_) & HASH_MASK;                         \
        h10 = (hx1_ ^ hy0_ ^ sd_) & HASH_MASK;                         \
        h01 = (hx0_ ^ hy1_ ^ sd_) & HASH_MASK;                         \
        h11 = (hx1_ ^ hy1_ ^ sd_) & HASH_MASK;                         \
    }

#define LOADS(h00, h10, h01, h11, f00, f10, f01, f11)                  \
    const float2 f00 = tab2[h00], f10 = tab2[h10],                     \
                 f01 = tab2[h01], f11 = tab2[h11];

#define STOREL(l, FX, FY, f00, f10, f01, f11)                          \
    {                                                                  \
        const float gx_ = 1.0f - FX, gy_ = 1.0f - FY;                  \
        const float w00_ = gx_ * gy_, w10_ = FX * gy_;                 \
        const float w01_ = gx_ * FY,  w11_ = FX * FY;                  \
        const float e0_ = w00_ * f00.x + w10_ * f10.x + w01_ * f01.x + w11_ * f11.x; \
        const float e1_ = w00_ * f00.y + w10_ * f10.y + w01_ * f01.y + w11_ * f11.y; \
        __builtin_nontemporal_store(e0_, outp + (size_t)(2 * (l)) * 65536u);     \
        __builtin_nontemporal_store(e1_, outp + (size_t)(2 * (l) + 1) * 65536u); \
    }

#define PAIR(la, lb)                                                   \
    {                                                                  \
        HASHES(la, a00, a10, a01, a11, fxa, fya)                       \
        HASHES(lb, b00, b10, b01, b11, fxb, fyb)                       \
        LOADS(a00, a10, a01, a11, fa00, fa10, fa01, fa11)              \
        LOADS(b00, b10, b01, b11, fb00, fb10, fb01, fb11)              \
        STOREL(la, fxa, fya, fa00, fa10, fa01, fa11)                   \
        STOREL(lb, fxb, fyb, fb00, fb10, fb01, fb11)                   \
    }

#define SINGLE(l)                                                      \
    {                                                                  \
        HASHES(l, c00, c10, c01, c11, fxc, fyc)                        \
        LOADS(c00, c10, c01, c11, fc00, fc10, fc01, fc11)              \
        STOREL(l, fxc, fyc, fc00, fc10, fc01, fc11)                    \
    }

__global__ __launch_bounds__(256) void lia_hashgrid_kernel(
    const float* __restrict__ x0,        // [B]
    const float* __restrict__ y0,        // [B]
    const float* __restrict__ tables,    // [T][2]
    const uint32_t* __restrict__ seeds,  // [16]
    const float* __restrict__ level_N,   // [16]
    const int* __restrict__ tile_p,      // scalar
    float* __restrict__ out)             // [B][32][65536]
{
    __shared__ float2 lds[1024];         // 8 KB, max strip cells = 992

    const int nbt = gridDim.x >> 8;      // 3*B
    const int bid = blockIdx.x;
    const int bt  = bid % nbt;           // consecutive blocks differ in third
    const int i   = bid / nbt;           // 0..255 (row)
    const int b   = bt / 3;
    const int third = bt % 3;
    const int j   = threadIdx.x;

    const float inv_tile = 1.0f / (float)(*tile_p);   // 1/1024, exact
    const float xb = x0[b];
    const float py = (float)i + y0[b];
    const float px = (float)j + xb;

    const float2* __restrict__ tab2 = (const float2*)tables;
    float* outp = out + (size_t)b * 32u * 65536u + (size_t)(i * 256 + j);

    // ---- coarse levels: metadata (all block-uniform) ----
    static const int LVT[3][4] = {{0,3,6,9},{1,4,7,10},{2,5,8,11}};
    int lv[4]; float sc[4]; uint32_t sd[4];
    int X0[4], IY[4], NX[4], OFF[4];
    int off = 0;
    #pragma unroll
    for (int k = 0; k < 4; ++k) {
        const int l = LVT[third][k];
        lv[k] = l;
        const float s = level_N[l] * inv_tile;
        sc[k] = s;
        sd[k] = seeds[l];
        X0[k] = (int)(xb * s);
        IY[k] = (int)(py * s);
        NX[k] = (int)((xb + 255.0f) * s) - X0[k] + 2;
        OFF[k] = off;
        off += 2 * NX[k];
    }

    // ---- cooperative LDS fill (~2-4 global lanes per thread) ----
    #pragma unroll
    for (int k = 0; k < 4; ++k) {
        const int nx = NX[k], tot = 2 * nx;
        for (int idx = j; idx < tot; idx += 256) {
            const int row = (idx >= nx) ? 1 : 0;
            const int col = idx - row * nx;
            const uint32_t ix = (uint32_t)(X0[k] + col);
            const uint32_t iy = (uint32_t)(IY[k] + row);
            const uint32_t h = (ix * PRIME1 ^ iy * PRIME2 ^ sd[k]) & HASH_MASK;
            lds[OFF[k] + idx] = tab2[h];
        }
    }
    __syncthreads();

    // ---- coarse levels: interpolate from LDS ----
    #pragma unroll
    for (int k = 0; k < 4; ++k) {
        const float s = sc[k];
        const float xn = px * s;
        const int ixl = (int)xn;
        const float fx = xn - (float)ixl;
        const float yn = py * s;
        const float fy = yn - (float)IY[k];
        const int c = OFF[k] + (ixl - X0[k]);
        const float2 f00 = lds[c];
        const float2 f10 = lds[c + 1];
        const float2 f01 = lds[c + NX[k]];
        const float2 f11 = lds[c + NX[k] + 1];
        const float gx = 1.0f - fx, gy = 1.0f - fy;
        const float w00 = gx * gy, w10 = fx * gy;
        const float w01 = gx * fy, w11 = fx * fy;
        const float e0 = w00 * f00.x + w10 * f10.x + w01 * f01.x + w11 * f11.x;
        const float e1 = w00 * f00.y + w10 * f10.y + w01 * f01.y + w11 * f11.y;
        __builtin_nontemporal_store(e0, outp + (size_t)(2 * lv[k]) * 65536u);
        __builtin_nontemporal_store(e1, outp + (size_t)(2 * lv[k] + 1) * 65536u);
    }

    // ---- fine levels: direct gathers (clustered) ----
    if (third == 0) {
        PAIR(12, 15)
    } else if (third == 1) {
        SINGLE(13)
    } else {
        SINGLE(14)
    }
}

extern "C" void kernel_launch(void* const* d_in, const int* in_sizes, int n_in,
                              void* d_out, int out_size, void* d_ws, size_t ws_size,
                              hipStream_t stream) {
    const float*    x0      = (const float*)d_in[0];
    const float*    y0      = (const float*)d_in[1];
    const float*    tables  = (const float*)d_in[2];
    const uint32_t* seeds   = (const uint32_t*)d_in[3];
    const float*    level_N = (const float*)d_in[4];
    const int*      tile_p  = (const int*)d_in[6];   // complete_tile_size
    float*          out     = (float*)d_out;

    const int B = in_sizes[0];                 // 8
    const int n_blocks = 256 * 3 * B;          // 6144 blocks = 24576 waves

    lia_hashgrid_kernel<<<n_blocks, 256, 0, stream>>>(
        x0, y0, tables, seeds, level_N, tile_p, out);
}

// Round 10
// 58.279 us; speedup vs baseline: 1.5650x; 1.1224x over previous
//
#include <hip/hip_runtime.h>
#include <stdint.h>

#define HASH_MASK 524287u
#define PRIME1 2654435761u
#define PRIME2 805459861u

// Output: [B][32][256][256] f32, channel c = 2*l + f.
// Block = 1024 threads = 4 rows x 256 cols of one image; 1 px/thread.
// Grid = B*64 = 512 blocks = 8192 waves = exactly 2 blocks/CU (full 2048 thr).
// Levels 0..11 staged in LDS once per 4-row block (strips <= 6400 float2),
// levels 12..15 (cells >= 2px, fully random) gathered directly.
// Model: machine serves ~1 unique divergent 64B line / ~2.5 cyc / CU;
// unique lines/px: fill ~5.2 + fine 16 + stores 2 (vs R9's ~27).

#define HASHES(l, h00, h10, h01, h11, FX, FY)                          \
    float FX, FY; uint32_t h00, h10, h01, h11;                         \
    {                                                                  \
        const float s_ = level_N[l] * inv_tile;                        \
        const float xn_ = px * s_, yn_ = py * s_;                      \
        const int ix_ = (int)xn_, iy_ = (int)yn_;   /* coords >= 0 */  \
        FX = xn_ - (float)ix_; FY = yn_ - (float)iy_;                  \
        const uint32_t hx0_ = (uint32_t)ix_ * PRIME1, hx1_ = hx0_ + PRIME1; \
        const uint32_t hy0_ = (uint32_t)iy_ * PRIME2, hy1_ = hy0_ + PRIME2; \
        const uint32_t sd_ = seeds[l];                                 \
        h00 = (hx0_ ^ hy0_ ^ sd_) & HASH_MASK;                         \
        h10 = (hx1_ ^ hy0_ ^ sd_) & HASH_MASK;                         \
        h01 = (hx0_ ^ hy1_ ^ sd_) & HASH_MASK;                         \
        h11 = (hx1_ ^ hy1_ ^ sd_) & HASH_MASK;                         \
    }

#define LOADS(h00, h10, h01, h11, f00, f10, f01, f11)                  \
    const float2 f00 = tab2[h00], f10 = tab2[h10],                     \
                 f01 = tab2[h01], f11 = tab2[h11];

#define STOREL(l, FX, FY, f00, f10, f01, f11)                          \
    {                                                                  \
        const float gx_ = 1.0f - FX, gy_ = 1.0f - FY;                  \
        const float w00_ = gx_ * gy_, w10_ = FX * gy_;                 \
        const float w01_ = gx_ * FY,  w11_ = FX * FY;                  \
        const float e0_ = w00_ * f00.x + w10_ * f10.x + w01_ * f01.x + w11_ * f11.x; \
        const float e1_ = w00_ * f00.y + w10_ * f10.y + w01_ * f01.y + w11_ * f11.y; \
        __builtin_nontemporal_store(e0_, outp + (size_t)(2 * (l)) * 65536u);     \
        __builtin_nontemporal_store(e1_, outp + (size_t)(2 * (l) + 1) * 65536u); \
    }

#define PAIR(la, lb)                                                   \
    {                                                                  \
        HASHES(la, a00, a10, a01, a11, fxa, fya)                       \
        HASHES(lb, b00, b10, b01, b11, fxb, fyb)                       \
        LOADS(a00, a10, a01, a11, fa00, fa10, fa01, fa11)              \
        LOADS(b00, b10, b01, b11, fb00, fb10, fb01, fb11)              \
        STOREL(la, fxa, fya, fa00, fa10, fa01, fa11)                   \
        STOREL(lb, fxb, fyb, fb00, fb10, fb01, fb11)                   \
    }

__global__ __launch_bounds__(1024, 8) void lia_hashgrid_kernel(
    const float* __restrict__ x0,        // [B]
    const float* __restrict__ y0,        // [B]
    const float* __restrict__ tables,    // [T][2]
    const uint32_t* __restrict__ seeds,  // [16]
    const float* __restrict__ level_N,   // [16]
    const int* __restrict__ tile_p,      // scalar
    float* __restrict__ out)             // [B][32][65536]
{
    __shared__ float2 lds[6400];         // 51.2 KB; worst-case strips 0..11

    const int bid = blockIdx.x;
    const int b   = bid >> 6;            // 0..7
    const int i0  = (bid & 63) << 2;     // block's first row
    const int tid = threadIdx.x;
    const int j   = tid & 255;
    const int r   = tid >> 8;            // 0..3
    const int i   = i0 + r;

    const float inv_tile = 1.0f / (float)(*tile_p);   // 1/1024, exact
    const float xb  = x0[b];                           // block-uniform
    const float py0 = (float)i0 + y0[b];               // block-uniform
    const float px = (float)j + xb;
    const float py = (float)i + y0[b];

    const float2* __restrict__ tab2 = (const float2*)tables;
    float* outp = out + (size_t)b * 32u * 65536u + (size_t)(i * 256 + j);

    // ---- pass 1: cooperative LDS fill of levels 0..11 strips ----
    {
        int off = 0;
        #pragma unroll
        for (int l = 0; l < 12; ++l) {
            const float s = level_N[l] * inv_tile;
            const uint32_t sd = seeds[l];
            const int X0 = (int)(xb * s);
            const int NX = (int)((xb + 255.0f) * s) - X0 + 2;
            const int Y0 = (int)(py0 * s);
            const int NY = (int)((py0 + 3.0f) * s) - Y0 + 2;
            const int cells = NY * NX;
            for (int idx = tid; idx < cells; idx += 1024) {
                const int row = idx / NX;          // NX block-uniform
                const int col = idx - row * NX;
                const uint32_t h = ((uint32_t)(X0 + col) * PRIME1
                                  ^ (uint32_t)(Y0 + row) * PRIME2 ^ sd) & HASH_MASK;
                lds[off + idx] = tab2[h];
            }
            off += cells;
        }
    }
    __syncthreads();

    // ---- pass 2: interpolate levels 0..11 from LDS ----
    {
        int off = 0;
        #pragma unroll
        for (int l = 0; l < 12; ++l) {
            const float s = level_N[l] * inv_tile;
            const int X0 = (int)(xb * s);
            const int NX = (int)((xb + 255.0f) * s) - X0 + 2;
            const int Y0 = (int)(py0 * s);
            const int NY = (int)((py0 + 3.0f) * s) - Y0 + 2;

            const float xn = px * s;
            const int ix = (int)xn;
            const float fx = xn - (float)ix;
            const float yn = py * s;
            const int iy = (int)yn;
            const float fy = yn - (float)iy;

            const int c = off + (iy - Y0) * NX + (ix - X0);
            const float2 f00 = lds[c];
            const float2 f10 = lds[c + 1];
            const float2 f01 = lds[c + NX];
            const float2 f11 = lds[c + NX + 1];

            const float gx = 1.0f - fx, gy = 1.0f - fy;
            const float w00 = gx * gy, w10 = fx * gy;
            const float w01 = gx * fy, w11 = fx * fy;
            const float e0 = w00 * f00.x + w10 * f10.x + w01 * f01.x + w11 * f11.x;
            const float e1 = w00 * f00.y + w10 * f10.y + w01 * f01.y + w11 * f11.y;
            __builtin_nontemporal_store(e0, outp + (size_t)(2 * l) * 65536u);
            __builtin_nontemporal_store(e1, outp + (size_t)(2 * l + 1) * 65536u);
            off += NY * NX;
        }
    }

    // ---- fine levels 12..15: direct random gathers (clustered pairs) ----
    PAIR(12, 13)
    PAIR(14, 15)
}

extern "C" void kernel_launch(void* const* d_in, const int* in_sizes, int n_in,
                              void* d_out, int out_size, void* d_ws, size_t ws_size,
                              hipStream_t stream) {
    const float*    x0      = (const float*)d_in[0];
    const float*    y0      = (const float*)d_in[1];
    const float*    tables  = (const float*)d_in[2];
    const uint32_t* seeds   = (const uint32_t*)d_in[3];
    const float*    level_N = (const float*)d_in[4];
    const int*      tile_p  = (const int*)d_in[6];   // complete_tile_size
    float*          out     = (float*)d_out;

    const int B = in_sizes[0];                 // 8
    const int n_blocks = B * 64;               // 512 blocks x 16 waves = 8192 waves

    lia_hashgrid_kernel<<<n_blocks, 1024, 0, stream>>>(
        x0, y0, tables, seeds, level_N, tile_p, out);
}